// Round 23
// baseline (60.182 us; speedup 1.0000x reference)
//
#include <hip/hip_runtime.h>
#include <stdint.h>

#define N_CAND 462080   // 16*76*76*5 = 1805*256 exactly
#define NBINS  2048
#define HPAD   16       // one hist bin per 64B line
#define TBLOCKS 96      // merged tail kernel: hist+cutoff+compact+NMS
#define TARGET 256u
#define SMAX   1024
#define SCORE_THR 0.02f
#define DEC_BLOCKS 1805 // = 8*225 + 5 (XCD swizzle: q=225, r=5)
// ctrl u32 indices, 64B apart (separate cache lines)
#define C_CNT 0    // compact count (hot atomic)
#define C_BIN 16   // cutoff bin
#define C_HD  32   // hist done-counter
#define C_CD  48   // compact done-counter
#define C_FLG 64   // cutoff-ready flag (own line)

// ---------------- ws layout (bytes) ----------------
// ctrl   : 128 x u32       @ 0       end 512
// hist   : 2048 x 16 u32   @ 512     end 131584  (padded; zeroed by decode blk 0)
// lscore : 1024 x f32      @ 131584  end 135680
// lidx   : 1024 x i32      @ 135680  end 139776
// scores : N x f32         @ 139776  end 1988096
// cls    : N x u8          @ 1988096 end 2450176  (~2.45 MB)
// No memset dispatch: decode block 0 re-arms C_HD/C_CD/C_FLG + zeroes hist
// every call; tail's elected block zeroes C_CNT and always writes C_BIN.

// ============ Kernel 1: decode — all-register cache-transpose + XCD swizzle ============
// BEST CONFIG (R20/R22: 57.4-57.7us, 9-variant ledger closed). Unchanged.
__global__ __launch_bounds__(256) void decode_kernel(
    const float* __restrict__ feats,
    float* __restrict__ scores, unsigned char* __restrict__ cls,
    unsigned int* __restrict__ ctrl, unsigned int* __restrict__ hist)
{
    const int t = threadIdx.x;
    const int bid = blockIdx.x;
    const int xcd = bid & 7, bix = bid >> 3;
    const int swz = (xcd < 5 ? xcd * 226 : 1130 + (xcd - 5) * 225) + bix; // bijective
    const int ci = swz * 256 + t;

    if (bid == 0) {   // re-arm counters + flag + zero padded hist
        if (t == 0) { ctrl[C_HD] = 0u; ctrl[C_CD] = 0u; ctrl[C_FLG] = 0u; }
        for (int i = t; i < NBINS; i += 256) hist[i * HPAD] = 0u;
    }

    // private row load starting at f[4] (f[0..3] are box coords: unused here)
    const float* __restrict__ fr = feats + (size_t)ci * 85;
    const float4* __restrict__ p = reinterpret_cast<const float4*>(fr + 4);
    float4 q[20];
#pragma unroll
    for (int i = 0; i < 20; ++i) q[i] = p[i];   // f[4..83]
    const float f84 = fr[84];                   // class 79

    // class argmax over classes 0..79, serial first-index chain
    float m = q[0].y; int cb = 0;
    if (q[0].z > m) { m = q[0].z; cb = 1; }
    if (q[0].w > m) { m = q[0].w; cb = 2; }
#pragma unroll
    for (int i = 1; i < 20; ++i) {
        const int b = i * 4 - 1;
        if (q[i].x > m) { m = q[i].x; cb = b; }
        if (q[i].y > m) { m = q[i].y; cb = b + 1; }
        if (q[i].z > m) { m = q[i].z; cb = b + 2; }
        if (q[i].w > m) { m = q[i].w; cb = b + 3; }
    }
    if (f84 > m) { m = f84; cb = 79; }

    // exp-sum of the 80 class logits (4 accumulators)
    float s0 = __expf(q[0].y - m);
    float s1 = __expf(q[0].z - m);
    float s2 = __expf(q[0].w - m);
    float s3 = 0.f;
#pragma unroll
    for (int i = 1; i < 20; ++i) {
        s0 += __expf(q[i].x - m);
        s1 += __expf(q[i].y - m);
        s2 += __expf(q[i].z - m);
        s3 += __expf(q[i].w - m);
    }
    s3 += __expf(f84 - m);
    const float ssum = (s0 + s1) + (s2 + s3);

    const float conf = 1.0f / (1.0f + __expf(-q[0].x));   // f[4]
    const float score = conf / ssum;                       // conf * max-softmax-prob
    scores[ci] = (score >= SCORE_THR) ? score : -1.0f;
    cls[ci] = (unsigned char)cb;
}

// box decode for one candidate (matches reference formulas, fp32)
__device__ inline float4 decode_box(const float* __restrict__ feats,
                                    const float* __restrict__ anchors, int ci)
{
    int a = ci % 5;
    int cell = ci / 5;
    int gx = cell % 76;
    int gy = (cell / 76) % 76;
    const float* f = feats + (long long)ci * 85;
    float bx = (1.0f / (1.0f + __expf(-f[0])) + (float)gx) / 76.0f;
    float by = (1.0f / (1.0f + __expf(-f[1])) + (float)gy) / 76.0f;
    float bw = __expf(f[2]) * anchors[2 * a]     / 76.0f;
    float bh = __expf(f[3]) * anchors[2 * a + 1] / 76.0f;
    return make_float4(by - bh * 0.5f, bx - bw * 0.5f,
                       by + bh * 0.5f, bx + bw * 0.5f);  // y1,x1,y2,x2
}

// ============ Kernel 2: merged tail — hist -> cutoff -> (flag) -> compact -> NMS ============
// One dispatch instead of two. Grid = 96 blocks <= 256 CUs: all blocks are
// resident before any polls -> the flag spin is deadlock-impossible (the
// flag-setter only waits on 96 unconditional election-counter arrivals).
// Fencing = the exact release/acquire pattern proven in R10-R22.
__global__ __launch_bounds__(1024) void tail_kernel(
    const float* __restrict__ scores, unsigned int* __restrict__ hist,
    unsigned int* __restrict__ ctrl,
    float* __restrict__ lscore, int* __restrict__ lidx,
    const float* __restrict__ feats, const float* __restrict__ anchors,
    const unsigned char* __restrict__ cls, float* __restrict__ out)
{
    __shared__ unsigned int lh[NBINS];          // 8 KB
    __shared__ unsigned int pa[1024], pb[1024]; // 8 KB ping-pong
    __shared__ unsigned long long wkey[16];
    __shared__ unsigned long long bkey;
    __shared__ float4 bbox;
    __shared__ int lastf;
    const int t = threadIdx.x;

    // ---- phase 1: histogram (LDS-private, spread global-atomic flush) ----
    lh[2 * t] = 0u; lh[2 * t + 1] = 0u;
    __syncthreads();
    for (int i = blockIdx.x * 1024 + t; i < N_CAND; i += TBLOCKS * 1024) {
        float s = scores[i];
        if (s >= SCORE_THR) {
            int bin = (int)(s * (float)NBINS);
            bin = bin > (NBINS - 1) ? (NBINS - 1) : bin;
            atomicAdd(&lh[bin], 1u);   // LDS atomic only
        }
    }
    __syncthreads();
    unsigned v0 = lh[2 * t], v1 = lh[2 * t + 1];
    if (v0) atomicAdd(&hist[(2 * t) * HPAD], v0);      // device-scope, spread
    if (v1) atomicAdd(&hist[(2 * t + 1) * HPAD], v1);
    __syncthreads();

    // ---- election 1: last-done block computes the cutoff ----
    if (t == 0) {
        __threadfence();                               // release
        unsigned old = atomicAdd(&ctrl[C_HD], 1u);
        lastf = (old == TBLOCKS - 1) ? 1 : 0;
    }
    __syncthreads();
    if (lastf) {
        if (t == 0) __threadfence();                   // acquire
        __syncthreads();
        unsigned b0 = hist[(2 * t) * HPAD];
        unsigned b1 = hist[(2 * t + 1) * HPAD];
        lh[2 * t] = b0; lh[2 * t + 1] = b1;
        pa[t] = b0 + b1;
        __syncthreads();
        unsigned int* srcb = pa; unsigned int* dstb = pb;
        for (int off = 1; off < 1024; off <<= 1) {
            unsigned v = srcb[t] + ((t + off < 1024) ? srcb[t + off] : 0u);
            dstb[t] = v;
            __syncthreads();
            unsigned int* tmp = srcb; srcb = dstb; dstb = tmp;
        }
        unsigned St = srcb[t];
        unsigned Sn = (t < 1023) ? srcb[t + 1] : 0u;
        if (t == 0) {
            ctrl[C_CNT] = 0u;                   // reset compact counter
            if (St < TARGET) ctrl[C_BIN] = 0u;  // total < TARGET -> keep all
        }
        if (St >= TARGET && Sn < TARGET) {      // unique crossing thread
            unsigned run = Sn + lh[2 * t + 1];
            ctrl[C_BIN] = (run >= TARGET) ? (unsigned)(2 * t + 1) : (unsigned)(2 * t);
        }
        __syncthreads();                        // C_BIN/C_CNT stores drained to L2
        if (t == 0) {
            __threadfence();                    // release cutoff results
            atomicExch(&ctrl[C_FLG], 1u);       // publish
        }
    }

    // ---- flag wait (all blocks; elected sees 1 immediately) ----
    if (t == 0) {
        while (atomicAdd(&ctrl[C_FLG], 0u) == 0u) __builtin_amdgcn_s_sleep(8);
        __threadfence();                               // acquire
    }
    __syncthreads();

    // ---- phase 2: compact (grid-stride) ----
    const int cut = (int)ctrl[C_BIN];
    for (int i = blockIdx.x * 1024 + t; i < N_CAND; i += TBLOCKS * 1024) {
        float sw = scores[i];
        if (sw >= SCORE_THR) {
            int bin = (int)(sw * (float)NBINS);
            bin = bin > (NBINS - 1) ? (NBINS - 1) : bin;
            if (bin >= cut) {
                unsigned pos = atomicAdd(&ctrl[C_CNT], 1u);
                if (pos < SMAX) { lscore[pos] = sw; lidx[pos] = i; }
            }
        }
    }
    __syncthreads();

    // ---- election 2: last-done block runs NMS ----
    if (t == 0) {
        __threadfence();                               // release
        unsigned old = atomicAdd(&ctrl[C_CD], 1u);
        lastf = (old == TBLOCKS - 1) ? 1 : 0;
    }
    __syncthreads();
    if (!lastf) return;
    if (t == 0) __threadfence();                       // acquire
    __syncthreads();

    unsigned cnt = ctrl[C_CNT];
    int n = (cnt < (unsigned)SMAX) ? (int)cnt : SMAX;

    unsigned long long key = 0ull;
    float4 mb = make_float4(0.f, 0.f, 0.f, 0.f);
    float  msc = 0.f, mcls = 0.f;
    unsigned midx = 0xFFFFFFFFu;
    bool aliveb = false;
    if (t < n) {
        msc  = lscore[t];
        midx = (unsigned)lidx[t];
        key  = ((unsigned long long)__float_as_uint(msc) << 32)
             | (unsigned long long)(0xFFFFFFFFu - midx);   // score desc, idx asc
        mb   = decode_box(feats, anchors, (int)midx);
        mcls = (float)cls[midx];
        aliveb = true;
    }

    for (int r = 0; r < 10; ++r) {
        unsigned long long k0 = aliveb ? key : 0ull;
#pragma unroll
        for (int msk = 32; msk > 0; msk >>= 1) {
            unsigned long long o = __shfl_xor(k0, msk);
            k0 = (o > k0) ? o : k0;
        }
        if ((t & 63) == 0) wkey[t >> 6] = k0;
        __syncthreads();
        if (t < 16) {
            unsigned long long v = wkey[t];
#pragma unroll
            for (int msk = 8; msk > 0; msk >>= 1) {
                unsigned long long o = __shfl_xor(v, msk);
                v = (o > v) ? o : v;
            }
            if (t == 0) bkey = v;
        }
        __syncthreads();

        unsigned long long wk = bkey;
        bool have = (wk != 0ull);
        unsigned widx = have ? (0xFFFFFFFFu - (unsigned)(wk & 0xFFFFFFFFull)) : 0xFFFFFFFFu;

        if (have && aliveb && midx == widx) {   // unique winner thread
            bbox = mb;
            out[r * 6 + 0] = mb.x;
            out[r * 6 + 1] = mb.y;
            out[r * 6 + 2] = mb.z;
            out[r * 6 + 3] = mb.w;
            out[r * 6 + 4] = msc;
            out[r * 6 + 5] = mcls;
            aliveb = false;
        }
        if (!have && t == 0) {
#pragma unroll
            for (int qq = 0; qq < 6; ++qq) out[r * 6 + qq] = 0.f;
        }
        __syncthreads();                        // bbox visible to all

        if (have && aliveb) {
            float4 ab = bbox;
            float aarea = fmaxf(ab.z - ab.x, 0.f) * fmaxf(ab.w - ab.y, 0.f);
            float iy1 = fmaxf(ab.x, mb.x);
            float ix1 = fmaxf(ab.y, mb.y);
            float iy2 = fminf(ab.z, mb.z);
            float ix2 = fminf(ab.w, mb.w);
            float inter = fmaxf(iy2 - iy1, 0.f) * fmaxf(ix2 - ix1, 0.f);
            float carea = fmaxf(mb.z - mb.x, 0.f) * fmaxf(mb.w - mb.y, 0.f);
            float iou = inter / (aarea + carea - inter + 1e-9f);
            if (iou > 0.5f) aliveb = false;
        }
    }
}

extern "C" void kernel_launch(void* const* d_in, const int* in_sizes, int n_in,
                              void* d_out, int out_size, void* d_ws, size_t ws_size,
                              hipStream_t stream) {
    const float* feats   = (const float*)d_in[0];
    const float* anchors = (const float*)d_in[1];
    char* ws = (char*)d_ws;

    unsigned int*   ctrl   = (unsigned int*)(ws + 0);
    unsigned int*   hist   = (unsigned int*)(ws + 512);
    float*          lscore = (float*)(ws + 131584);
    int*            lidx   = (int*)(ws + 135680);
    float*          scores = (float*)(ws + 139776);
    unsigned char*  cls    = (unsigned char*)(ws + 1988096);
    float*          out    = (float*)d_out;

    decode_kernel <<<DEC_BLOCKS, 256, 0, stream>>>(feats, scores, cls, ctrl, hist);
    tail_kernel   <<<TBLOCKS, 1024, 0, stream>>>(scores, hist, ctrl, lscore, lidx,
                                                 feats, anchors, cls, out);
}

// Round 24
// 57.223 us; speedup vs baseline: 1.0517x; 1.0517x over previous
//
#include <hip/hip_runtime.h>
#include <stdint.h>

#define N_CAND 462080   // 16*76*76*5 = 1805*256 exactly
#define NBINS  2048
#define HPAD   16       // one hist bin per 64B line
#define HIST_BLOCKS 96
#define COMPACT_BLOCKS 64
#define TARGET 256u
#define SMAX   1024
#define SCORE_THR 0.02f
#define DEC_BLOCKS 1805 // = 8*225 + 5 (XCD swizzle: q=225, r=5)
// ctrl u32 indices, 64B apart (separate cache lines)
#define C_CNT 0    // compact count (hot atomic)
#define C_BIN 16   // cutoff bin
#define C_HD  32   // hist done-counter
#define C_CD  48   // compact done-counter

// ---------------- ws layout (bytes) ----------------
// ctrl   : 64 x u32        @ 0       end 256
// hist   : 2048 x 16 u32   @ 256     end 131328  (padded; zeroed by decode blk 0)
// lscore : 1024 x f32      @ 131328  end 135424
// lidx   : 1024 x i32      @ 135424  end 139520
// scores : N x f32         @ 139520  end 1987840
// cls    : N x u8          @ 1987840 end 2449920  (~2.45 MB)

// ============ Kernel 1: decode — all-register cache-transpose + XCD swizzle ============
// FINAL CONFIG (R20/R22: 57.4-57.7us). 9-variant decode ledger closed
// (structure-invariant); R23's merged tail regressed (dispatch boundaries are
// ~free; in-kernel flag-spin handoff costs more) -> 3-dispatch layout final.
__global__ __launch_bounds__(256) void decode_kernel(
    const float* __restrict__ feats,
    float* __restrict__ scores, unsigned char* __restrict__ cls,
    unsigned int* __restrict__ ctrl, unsigned int* __restrict__ hist)
{
    const int t = threadIdx.x;
    const int bid = blockIdx.x;
    const int xcd = bid & 7, bix = bid >> 3;
    const int swz = (xcd < 5 ? xcd * 226 : 1130 + (xcd - 5) * 225) + bix; // bijective
    const int ci = swz * 256 + t;

    if (bid == 0) {   // re-arm counters + zero padded hist (kernel 2 reads)
        if (t == 0) { ctrl[C_HD] = 0u; ctrl[C_CD] = 0u; }
        for (int i = t; i < NBINS; i += 256) hist[i * HPAD] = 0u;
    }

    // private row load starting at f[4] (f[0..3] are box coords: unused here)
    const float* __restrict__ fr = feats + (size_t)ci * 85;
    const float4* __restrict__ p = reinterpret_cast<const float4*>(fr + 4);
    float4 q[20];
#pragma unroll
    for (int i = 0; i < 20; ++i) q[i] = p[i];   // f[4..83]
    const float f84 = fr[84];                   // class 79

    // class argmax over classes 0..79, serial first-index chain
    // q[0]: .x=f4(conf), .y/.z/.w = classes 0,1,2 ; q[i>=1]: classes 4i-1..4i+2
    float m = q[0].y; int cb = 0;
    if (q[0].z > m) { m = q[0].z; cb = 1; }
    if (q[0].w > m) { m = q[0].w; cb = 2; }
#pragma unroll
    for (int i = 1; i < 20; ++i) {
        const int b = i * 4 - 1;
        if (q[i].x > m) { m = q[i].x; cb = b; }
        if (q[i].y > m) { m = q[i].y; cb = b + 1; }
        if (q[i].z > m) { m = q[i].z; cb = b + 2; }
        if (q[i].w > m) { m = q[i].w; cb = b + 3; }
    }
    if (f84 > m) { m = f84; cb = 79; }

    // exp-sum of the 80 class logits (4 accumulators)
    float s0 = __expf(q[0].y - m);
    float s1 = __expf(q[0].z - m);
    float s2 = __expf(q[0].w - m);
    float s3 = 0.f;
#pragma unroll
    for (int i = 1; i < 20; ++i) {
        s0 += __expf(q[i].x - m);
        s1 += __expf(q[i].y - m);
        s2 += __expf(q[i].z - m);
        s3 += __expf(q[i].w - m);
    }
    s3 += __expf(f84 - m);
    const float ssum = (s0 + s1) + (s2 + s3);

    const float conf = 1.0f / (1.0f + __expf(-q[0].x));   // f[4]
    const float score = conf / ssum;                       // conf * max-softmax-prob
    scores[ci] = (score >= SCORE_THR) ? score : -1.0f;
    cls[ci] = (unsigned char)cb;
}

// ============ Kernel 2: histogram (96 blocks, spread flush) + elected cutoff ============
__global__ __launch_bounds__(1024) void hist_cutoff_kernel(
    const float* __restrict__ scores, unsigned int* __restrict__ hist,
    unsigned int* __restrict__ ctrl)
{
    __shared__ unsigned int lh[NBINS];          // 8 KB
    __shared__ unsigned int pa[1024], pb[1024]; // 8 KB ping-pong
    __shared__ int lastf;
    const int t = threadIdx.x;

    lh[2 * t] = 0u; lh[2 * t + 1] = 0u;
    __syncthreads();

    for (int i = blockIdx.x * 1024 + t; i < N_CAND; i += HIST_BLOCKS * 1024) {
        float s = scores[i];
        if (s >= SCORE_THR) {
            int bin = (int)(s * (float)NBINS);
            bin = bin > (NBINS - 1) ? (NBINS - 1) : bin;
            atomicAdd(&lh[bin], 1u);   // LDS atomic only
        }
    }
    __syncthreads();
    unsigned v0 = lh[2 * t], v1 = lh[2 * t + 1];
    if (v0) atomicAdd(&hist[(2 * t) * HPAD], v0);      // device-scope, spread
    if (v1) atomicAdd(&hist[(2 * t + 1) * HPAD], v1);
    __syncthreads();

    if (t == 0) {
        __threadfence();                               // release
        unsigned old = atomicAdd(&ctrl[C_HD], 1u);
        lastf = (old == HIST_BLOCKS - 1) ? 1 : 0;
    }
    __syncthreads();
    if (!lastf) return;
    if (t == 0) __threadfence();                       // acquire
    __syncthreads();

    // ---- cutoff scan (elected block): 2 loads/thread ----
    unsigned b0 = hist[(2 * t) * HPAD];
    unsigned b1 = hist[(2 * t + 1) * HPAD];
    lh[2 * t] = b0; lh[2 * t + 1] = b1;
    pa[t] = b0 + b1;
    __syncthreads();

    unsigned int* srcb = pa; unsigned int* dstb = pb;
    for (int off = 1; off < 1024; off <<= 1) {
        unsigned v = srcb[t] + ((t + off < 1024) ? srcb[t + off] : 0u);
        dstb[t] = v;
        __syncthreads();
        unsigned int* tmp = srcb; srcb = dstb; dstb = tmp;
    }
    unsigned St = srcb[t];
    unsigned Sn = (t < 1023) ? srcb[t + 1] : 0u;

    if (t == 0) {
        ctrl[C_CNT] = 0u;
        if (St < TARGET) ctrl[C_BIN] = 0u;
    }
    if (St >= TARGET && Sn < TARGET) {
        unsigned run = Sn + lh[2 * t + 1];
        ctrl[C_BIN] = (run >= TARGET) ? (unsigned)(2 * t + 1) : (unsigned)(2 * t);
    }
}

// box decode for one candidate (matches reference formulas, fp32)
__device__ inline float4 decode_box(const float* __restrict__ feats,
                                    const float* __restrict__ anchors, int ci)
{
    int a = ci % 5;
    int cell = ci / 5;
    int gx = cell % 76;
    int gy = (cell / 76) % 76;
    const float* f = feats + (long long)ci * 85;
    float bx = (1.0f / (1.0f + __expf(-f[0])) + (float)gx) / 76.0f;
    float by = (1.0f / (1.0f + __expf(-f[1])) + (float)gy) / 76.0f;
    float bw = __expf(f[2]) * anchors[2 * a]     / 76.0f;
    float bh = __expf(f[3]) * anchors[2 * a + 1] / 76.0f;
    return make_float4(by - bh * 0.5f, bx - bw * 0.5f,
                       by + bh * 0.5f, bx + bw * 0.5f);  // y1,x1,y2,x2
}

// ============ Kernel 3: compact (grid-stride) + elected sort-free NMS ============
__global__ __launch_bounds__(1024) void compact_nms_kernel(
    const float* __restrict__ scores, unsigned int* __restrict__ ctrl,
    float* __restrict__ lscore, int* __restrict__ lidx,
    const float* __restrict__ feats, const float* __restrict__ anchors,
    const unsigned char* __restrict__ cls, float* __restrict__ out)
{
    __shared__ unsigned long long wkey[16];
    __shared__ unsigned long long bkey;
    __shared__ float4 bbox;
    __shared__ int lastf;
    const int t = threadIdx.x;

    const int cut = (int)ctrl[C_BIN];
    for (int i = blockIdx.x * 1024 + t; i < N_CAND; i += COMPACT_BLOCKS * 1024) {
        float sw = scores[i];
        if (sw >= SCORE_THR) {
            int bin = (int)(sw * (float)NBINS);
            bin = bin > (NBINS - 1) ? (NBINS - 1) : bin;
            if (bin >= cut) {
                unsigned pos = atomicAdd(&ctrl[C_CNT], 1u);
                if (pos < SMAX) { lscore[pos] = sw; lidx[pos] = i; }
            }
        }
    }
    __syncthreads();
    if (t == 0) {
        __threadfence();                               // release
        unsigned old = atomicAdd(&ctrl[C_CD], 1u);
        lastf = (old == COMPACT_BLOCKS - 1) ? 1 : 0;
    }
    __syncthreads();
    if (!lastf) return;
    if (t == 0) __threadfence();                       // acquire
    __syncthreads();

    // ---- NMS phase (1024 threads, 1 candidate/thread) ----
    unsigned cnt = ctrl[C_CNT];
    int n = (cnt < (unsigned)SMAX) ? (int)cnt : SMAX;

    unsigned long long key = 0ull;
    float4 mb = make_float4(0.f, 0.f, 0.f, 0.f);
    float  msc = 0.f, mcls = 0.f;
    unsigned midx = 0xFFFFFFFFu;
    bool aliveb = false;
    if (t < n) {
        msc  = lscore[t];
        midx = (unsigned)lidx[t];
        key  = ((unsigned long long)__float_as_uint(msc) << 32)
             | (unsigned long long)(0xFFFFFFFFu - midx);   // score desc, idx asc
        mb   = decode_box(feats, anchors, (int)midx);
        mcls = (float)cls[midx];
        aliveb = true;
    }

    for (int r = 0; r < 10; ++r) {
        unsigned long long k0 = aliveb ? key : 0ull;
#pragma unroll
        for (int msk = 32; msk > 0; msk >>= 1) {
            unsigned long long o = __shfl_xor(k0, msk);
            k0 = (o > k0) ? o : k0;
        }
        if ((t & 63) == 0) wkey[t >> 6] = k0;
        __syncthreads();
        if (t < 16) {
            unsigned long long v = wkey[t];
#pragma unroll
            for (int msk = 8; msk > 0; msk >>= 1) {
                unsigned long long o = __shfl_xor(v, msk);
                v = (o > v) ? o : v;
            }
            if (t == 0) bkey = v;
        }
        __syncthreads();

        unsigned long long wk = bkey;
        bool have = (wk != 0ull);
        unsigned widx = have ? (0xFFFFFFFFu - (unsigned)(wk & 0xFFFFFFFFull)) : 0xFFFFFFFFu;

        if (have && aliveb && midx == widx) {   // unique winner thread
            bbox = mb;
            out[r * 6 + 0] = mb.x;
            out[r * 6 + 1] = mb.y;
            out[r * 6 + 2] = mb.z;
            out[r * 6 + 3] = mb.w;
            out[r * 6 + 4] = msc;
            out[r * 6 + 5] = mcls;
            aliveb = false;
        }
        if (!have && t == 0) {
#pragma unroll
            for (int q = 0; q < 6; ++q) out[r * 6 + q] = 0.f;
        }
        __syncthreads();                        // bbox visible to all

        if (have && aliveb) {
            float4 ab = bbox;
            float aarea = fmaxf(ab.z - ab.x, 0.f) * fmaxf(ab.w - ab.y, 0.f);
            float iy1 = fmaxf(ab.x, mb.x);
            float ix1 = fmaxf(ab.y, mb.y);
            float iy2 = fminf(ab.z, mb.z);
            float ix2 = fminf(ab.w, mb.w);
            float inter = fmaxf(iy2 - iy1, 0.f) * fmaxf(ix2 - ix1, 0.f);
            float carea = fmaxf(mb.z - mb.x, 0.f) * fmaxf(mb.w - mb.y, 0.f);
            float iou = inter / (aarea + carea - inter + 1e-9f);
            if (iou > 0.5f) aliveb = false;
        }
    }
}

extern "C" void kernel_launch(void* const* d_in, const int* in_sizes, int n_in,
                              void* d_out, int out_size, void* d_ws, size_t ws_size,
                              hipStream_t stream) {
    const float* feats   = (const float*)d_in[0];
    const float* anchors = (const float*)d_in[1];
    char* ws = (char*)d_ws;

    unsigned int*   ctrl   = (unsigned int*)(ws + 0);
    unsigned int*   hist   = (unsigned int*)(ws + 256);
    float*          lscore = (float*)(ws + 131328);
    int*            lidx   = (int*)(ws + 135424);
    float*          scores = (float*)(ws + 139520);
    unsigned char*  cls    = (unsigned char*)(ws + 1987840);
    float*          out    = (float*)d_out;

    decode_kernel      <<<DEC_BLOCKS, 256, 0, stream>>>(feats, scores, cls, ctrl, hist);
    hist_cutoff_kernel <<<HIST_BLOCKS, 1024, 0, stream>>>(scores, hist, ctrl);
    compact_nms_kernel <<<COMPACT_BLOCKS, 1024, 0, stream>>>(scores, ctrl, lscore, lidx,
                                                             feats, anchors, cls, out);
}